// Round 2
// baseline (120.613 us; speedup 1.0000x reference)
//
#include <hip/hip_runtime.h>
#include <stdint.h>
#include <stddef.h>

#define BB 16384
#define CC 500
#define DD 512
#define PADC 512
#define LMARGIN 1.0f
#define EPSQ 1e-12f

// loss kernel geometry: 256 blocks x 512 threads (8 waves)
// wave = (mtile in {0,1}: 32 rows each) x (cquar in {0..3}: 128 cols each)
#define ROWS_PER_BLOCK 64
#define NG 8                 // 16-proto groups per C-quarter
#define NKQ 4                // K quarters of 128
#define NIT (NG * NKQ)       // 32 iterations
#define QUADB 1056           // 4 proto-rows x 256B data + 32B pad
#define UNITB (4 * QUADB)    // stage unit: 16 protos x 128 k = 4224 B
#define NRING 3

typedef __attribute__((ext_vector_type(8))) _Float16 f16x8;
typedef __attribute__((ext_vector_type(4))) float f32x4;

#define GLOBAL_AS __attribute__((address_space(1)))
#define LDS_AS __attribute__((address_space(3)))

__device__ __forceinline__ void ld_lds16(const void* g, void* l) {
  __builtin_amdgcn_global_load_lds((const GLOBAL_AS void*)g, (LDS_AS void*)l, 16, 0, 0);
}

__device__ __forceinline__ unsigned short f2h_bits(float f) {
  union { _Float16 h; unsigned short u; } v;
  v.h = (_Float16)f;
  return v.u;
}

// ---- pre-kernel: prototypes fp32 -> f16 (padded to 512 rows), p2[] fp32, zero out ----
__global__ void prep_kernel(const float* __restrict__ protos,
                            unsigned short* __restrict__ protoH,
                            float* __restrict__ p2,
                            float* __restrict__ out) {
  int c = blockIdx.x;    // 0..511
  int t = threadIdx.x;   // 0..255, each handles 2 dims
  if (c == 0 && t == 0) out[0] = 0.f;
  float v0 = 0.f, v1 = 0.f;
  if (c < CC) {
    v0 = protos[c * DD + 2 * t];
    v1 = protos[c * DD + 2 * t + 1];
  }
  unsigned pk = (unsigned)f2h_bits(v0) | ((unsigned)f2h_bits(v1) << 16);
  ((unsigned*)protoH)[c * (DD / 2) + t] = pk;
  float s = v0 * v0 + v1 * v1;
#pragma unroll
  for (int d = 1; d < 64; d <<= 1) s += __shfl_xor(s, d, 64);
  __shared__ float ws4[4];
  if ((t & 63) == 0) ws4[t >> 6] = s;
  __syncthreads();
  if (t == 0) p2[c] = ws4[0] + ws4[1] + ws4[2] + ws4[3];
}

// ---- main kernel ----
__launch_bounds__(512, 2)
__global__ void loss_kernel(const float* __restrict__ feat,
                            const int* __restrict__ labels,
                            const unsigned short* __restrict__ protoH,
                            const float* __restrict__ p2,
                            float* __restrict__ out) {
  // 4 quarters x 3-ring x 4224B = 50688B
  __shared__ __align__(16) unsigned char ldsB[4 * NRING * UNITB];
  __shared__ float p2s[PADC];        // 2KB
  __shared__ float f2s[ROWS_PER_BLOCK];
  __shared__ float redMin[4][ROWS_PER_BLOCK];
  __shared__ float redPos[4][ROWS_PER_BLOCK];

  const int tid = threadIdx.x;
  const int w = tid >> 6;
  const int lane = tid & 63;
  const int lane16 = lane & 15;
  const int quad = lane >> 4;
  const int mtile = w & 1;           // which 32-row half
  const int cq = w >> 1;             // which 128-col quarter
  const int rowBase = blockIdx.x * ROWS_PER_BLOCK + mtile * 32;

  // ---- stage iteration 0 (group 0, kq 0) into ring slot 0 ----
  // wave stages 2 of the 4 row-quads of its own quarter's unit
  {
    const int g = 0, kq = 0;
#pragma unroll
    for (int jj = 0; jj < 2; ++jj) {
      int j = 2 * mtile + jj;                 // row-quad 0..3
      int r = 4 * j + (lane >> 4);            // proto row in group 0..15
      const unsigned short* src = protoH +
          (size_t)(cq * 128 + g * 16 + r) * DD + kq * 128 + (lane & 15) * 8;
      ld_lds16(src, ldsB + (cq * NRING + 0) * UNITB + j * QUADB);
    }
  }

  // ---- p2 to LDS (512 threads, 1 each) ----
  p2s[tid] = p2[tid];

  // ---- A fragments in registers: 2 tiles x 16 k-chunks, + f2 ----
  // lane holds A[m=lane16][k = j*32 + quad*8 + 0..7] for rows rowBase + t*16 + lane16
  f16x8 afrag[2][16];
  float f2part[2] = {0.f, 0.f};
#pragma unroll
  for (int t = 0; t < 2; ++t) {
    const float* frow = feat + (size_t)(rowBase + t * 16 + lane16) * DD;
#pragma unroll
    for (int j = 0; j < 16; ++j) {
      const int k0 = j * 32 + quad * 8;
      f32x4 a0 = *(const f32x4*)(frow + k0);
      f32x4 a1 = *(const f32x4*)(frow + k0 + 4);
      f16x8 af;
#pragma unroll
      for (int u = 0; u < 4; ++u) {
        af[u] = (_Float16)a0[u];
        af[u + 4] = (_Float16)a1[u];
        f2part[t] = fmaf(a0[u], a0[u], f2part[t]);
        f2part[t] = fmaf(a1[u], a1[u], f2part[t]);
      }
      afrag[t][j] = af;
    }
    // combine quads (each covered a quarter of k)
    f2part[t] += __shfl_xor(f2part[t], 16, 64);
    f2part[t] += __shfl_xor(f2part[t], 32, 64);
    if (quad == 0) f2s[mtile * 32 + t * 16 + lane16] = f2part[t];
  }

  // labels for my 8 output rows (C/D layout: row = quad*4 + i, col = lane16)
  int lab[2][4];
#pragma unroll
  for (int t = 0; t < 2; ++t)
#pragma unroll
    for (int i = 0; i < 4; ++i)
      lab[t][i] = labels[rowBase + t * 16 + quad * 4 + i];

  f32x4 acc[2][2];
#pragma unroll
  for (int t = 0; t < 2; ++t)
#pragma unroll
    for (int h = 0; h < 2; ++h)
      acc[t][h] = (f32x4){0.f, 0.f, 0.f, 0.f};

  float runMin[2][4], posD[2][4];
#pragma unroll
  for (int t = 0; t < 2; ++t)
#pragma unroll
    for (int i = 0; i < 4; ++i) { runMin[t][i] = 1e30f; posD[t][i] = -1e30f; }

  float f2r[2][4];

  int ring = 0;
  for (int it = 0; it < NIT; ++it) {
    // barrier: (a) drains my own staging loads for buf `ring` (vmcnt 0 at the
    // implicit pre-barrier wait), (b) all waves past compute(it-1) -> safe to
    // overwrite ring slot (it+1)%3 (last read at it-2).
    __syncthreads();

    const int ringNext = (ring + 1 == NRING) ? 0 : ring + 1;
    if (it + 1 < NIT) {
      const int it1 = it + 1;
      const int g1 = it1 >> 2, kq1 = it1 & 3;
#pragma unroll
      for (int jj = 0; jj < 2; ++jj) {
        int j = 2 * mtile + jj;
        int r = 4 * j + (lane >> 4);
        const unsigned short* src = protoH +
            (size_t)(cq * 128 + g1 * 16 + r) * DD + kq1 * 128 + (lane & 15) * 8;
        ld_lds16(src, ldsB + (cq * NRING + ringNext) * UNITB + j * QUADB);
      }
    }

    // ---- compute current unit: 4 k-steps, B shared across both M-tiles ----
    const int g = it >> 2, kq = it & 3;
    const unsigned char* base = ldsB + (cq * NRING + ring) * UNITB +
                                (lane16 >> 2) * QUADB + (lane16 & 3) * 256 +
                                quad * 16;
#pragma unroll
    for (int s = 0; s < 4; ++s) {
      f16x8 b = *(const f16x8*)(base + s * 64);
      acc[0][s & 1] = __builtin_amdgcn_mfma_f32_16x16x32_f16(afrag[0][kq * 4 + s], b, acc[0][s & 1], 0, 0, 0);
      acc[1][s & 1] = __builtin_amdgcn_mfma_f32_16x16x32_f16(afrag[1][kq * 4 + s], b, acc[1][s & 1], 0, 0, 0);
    }

    if (kq == 3) {
      // group g finished: epilogue in registers
      if (it == 3) {  // first epilogue: f2s is valid (first __syncthreads passed)
#pragma unroll
        for (int t = 0; t < 2; ++t)
#pragma unroll
          for (int i = 0; i < 4; ++i)
            f2r[t][i] = f2s[mtile * 32 + t * 16 + quad * 4 + i];
      }
      const int col = cq * 128 + g * 16 + lane16;
      const float p2c = p2s[col];
      const bool colOk = (col < CC);
#pragma unroll
      for (int t = 0; t < 2; ++t) {
#pragma unroll
        for (int i = 0; i < 4; ++i) {
          float dot = acc[t][0][i] + acc[t][1][i];
          float d = sqrtf(fmaxf(f2r[t][i] + p2c - 2.f * dot, EPSQ));
          bool isPos = (col == lab[t][i]);
          posD[t][i] = fmaxf(posD[t][i], isPos ? d : -1e30f);
          runMin[t][i] = fminf(runMin[t][i], (!isPos && colOk) ? d : 1e30f);
        }
#pragma unroll
        for (int h = 0; h < 2; ++h) acc[t][h] = (f32x4){0.f, 0.f, 0.f, 0.f};
      }
    }
    ring = ringNext;
  }

  // ---- cross-lane reduce over the 16 cols held in each quad's lanes ----
#pragma unroll
  for (int t = 0; t < 2; ++t) {
#pragma unroll
    for (int i = 0; i < 4; ++i) {
      float m = runMin[t][i], p = posD[t][i];
#pragma unroll
      for (int d = 1; d < 16; d <<= 1) {
        m = fminf(m, __shfl_xor(m, d, 64));
        p = fmaxf(p, __shfl_xor(p, d, 64));
      }
      if (lane16 == 0) {
        int r = mtile * 32 + t * 16 + quad * 4 + i;
        redMin[cq][r] = m;
        redPos[cq][r] = p;
      }
    }
  }
  __syncthreads();

  // ---- combine the 4 C-quarters, one lane per row, single atomic ----
  if (tid < 64) {
    float m = fminf(fminf(redMin[0][tid], redMin[1][tid]),
                    fminf(redMin[2][tid], redMin[3][tid]));
    float p = fmaxf(fmaxf(redPos[0][tid], redPos[1][tid]),
                    fmaxf(redPos[2][tid], redPos[3][tid]));
    float term = fmaxf(p - m + LMARGIN, 0.f);
#pragma unroll
    for (int d = 1; d < 64; d <<= 1) term += __shfl_xor(term, d, 64);
    if (tid == 0) atomicAdd(out, term * (1.0f / BB));
  }
}

extern "C" void kernel_launch(void* const* d_in, const int* in_sizes, int n_in,
                              void* d_out, int out_size, void* d_ws, size_t ws_size,
                              hipStream_t stream) {
  const float* feat = (const float*)d_in[0];
  const float* protos = (const float*)d_in[1];
  const int* labels = (const int*)d_in[2];
  float* out = (float*)d_out;

  unsigned short* protoH = (unsigned short*)d_ws;  // 512*512*2 B
  float* p2 = (float*)((char*)d_ws + (size_t)PADC * DD * sizeof(unsigned short));

  prep_kernel<<<PADC, 256, 0, stream>>>(protos, protoH, p2, out);
  loss_kernel<<<BB / ROWS_PER_BLOCK, 512, 0, stream>>>(feat, labels, protoH, p2, out);
}